// Round 17
// baseline (21258.846 us; speedup 1.0000x reference)
//
#include <hip/hip_runtime.h>
#include <hip/hip_bf16.h>
#include <hip/hip_cooperative_groups.h>

namespace cg = cooperative_groups;

typedef __bf16 bf16_t;
typedef __bf16 bf16x8 __attribute__((ext_vector_type(8)));
typedef float f32x4 __attribute__((ext_vector_type(4)));

#define TLEN 128
#define BATCHN 512
#define OBS 256
#define HID 1024
#define STATEDIM 1024
#define ROWS (TLEN * BATCHN)   // 65536
#define RKDT 0.25f

// EPI_Z0 : Z0f=v+b (f32) AND h1=tanh(v+b)      (step-0, split-z K=2048)
// EPI_B16: outB = bf16(v)                      (W20T precompute)
// EPI_F1 : N=2048 fused [k1|G1]: KACC=(dt/6)k; GACC=(dt/6)G; h1=tanh(Z0+kgc*G)
// EPI_F23: N=2048 fused [k|G]:  KACC+=(dt/3)k; GACC+=(dt/3)G; h1=tanh(Z0+kgc*G)
// EPI_F4 : N=2048 fused [k4|G4]: Zf=Zf+KACC+(dt/6)k4;
//          Z0+=GACC+(dt/6)G4; h1_next=tanh(Z0_new)
// EPI_K4L: N=1024 final k4: zn=Zf+KACC+(dt/6)k4 -> Zf; write split-z S2
enum { EPI_F32 = 0, EPI_GI, EPI_TANH, EPI_B16, EPI_Z0, EPI_F1, EPI_F23, EPI_F4, EPI_K4L };

__device__ __forceinline__ void gload_lds16(const bf16_t* g, bf16_t* l) {
  __builtin_amdgcn_global_load_lds(
      (const __attribute__((address_space(1))) void*)g,
      (__attribute__((address_space(3))) void*)l, 16, 0, 0);
}

__device__ __forceinline__ bf16_t f2bf(float x) { return (bf16_t)x; }

// fast tanh/sigmoid on v_exp_f32 (~1e-6 abs err; bf16-invisible)
__device__ __forceinline__ float fast_tanh(float x) {
  const float e = __expf(2.f * x);
  return 1.f - 2.f / (e + 1.f);
}
__device__ __forceinline__ float fast_sigmoid(float x) {
  return 1.f / (1.f + __expf(-x));
}

#define MF(a_, b_, c_) __builtin_amdgcn_mfma_f32_16x16x32_bf16(a_, b_, c_, 0, 0, 0)

// ============================================================================
// m97-structure GEMM + bijective XCD chunk-swizzle (proven r7/r16 main loop).
// C = epi(A[M][K] @ Wt[N][K]^T + bias). A,Wt bf16 row-major, fp32 acc.
// 128x128 tile, BK=32, 4 waves (2x2), 16x16x32 MFMA, global_load_lds dbuf.
// Zf/Z0/KACC/GACC are same-thread RMW in some epilogues -> not __restrict__.
// Fused [k|G] epilogues: block-uniform branch on c<1024 (n0 aligned 128).
// ============================================================================
template<int EPI>
__global__ __launch_bounds__(256)
void gemm_bt(const bf16_t* __restrict__ A, const bf16_t* __restrict__ Wt,
             const float* __restrict__ bias, int M, int N, int K,
             float* outF, bf16_t* __restrict__ outB,
             float* Z, float* Z0, bf16_t* S2,
             float* KACC, float* GACC,
             float kgc, int last)
{
  __shared__ __align__(16) bf16_t As[2][128 * 32];
  __shared__ __align__(16) bf16_t Bs[2][128 * 32];
  const int tid = threadIdx.x;
  const int lane = tid & 63;
  const int wave = tid >> 6;
  const int nbn = N >> 7;

  // bijective XCD swizzle (m204)
  int bid = blockIdx.x;
  {
    const int nwg = gridDim.x;
    const int q = nwg >> 3, r = nwg & 7;
    const int xcd = bid & 7, lid = bid >> 3;
    bid = (xcd < r ? xcd * (q + 1) : r * (q + 1) + (xcd - r) * q) + lid;
  }
  const int bm = bid / nbn;
  const int bn = bid % nbn;
  const int m0 = bm << 7, n0 = bn << 7;
  const int wr = wave >> 1, wc = wave & 1;
  const int srow = tid >> 2;
  const int scol = (tid & 3) << 3;

  f32x4 acc[4][4] = {};
  const int nk = K >> 5;
  int cur = 0;

  {
    const bf16_t* ga = A  + (size_t)(m0 + srow) * K + scol;
    const bf16_t* gb = Wt + (size_t)(n0 + srow) * K + scol;
    bf16_t* la = &As[0][tid * 8];
    bf16_t* lb = &Bs[0][tid * 8];
    gload_lds16(ga, la);
    gload_lds16(ga + (size_t)64 * K, la + 2048);
    gload_lds16(gb, lb);
    gload_lds16(gb + (size_t)64 * K, lb + 2048);
  }

  for (int ks = 0; ks < nk; ++ks) {
    __syncthreads();  // drains vmcnt(0): staged tile ready
    if (ks + 1 < nk) {
      const bf16_t* ga = A  + (size_t)(m0 + srow) * K + (ks + 1) * 32 + scol;
      const bf16_t* gb = Wt + (size_t)(n0 + srow) * K + (ks + 1) * 32 + scol;
      bf16_t* la = &As[cur ^ 1][tid * 8];
      bf16_t* lb = &Bs[cur ^ 1][tid * 8];
      gload_lds16(ga, la);
      gload_lds16(ga + (size_t)64 * K, la + 2048);
      gload_lds16(gb, lb);
      gload_lds16(gb + (size_t)64 * K, lb + 2048);
    }
    const int kb = (lane >> 4) << 3;
    const int rr = lane & 15;
    bf16x8 af[4], bfr[4];
#pragma unroll
    for (int i = 0; i < 4; ++i) {
      af[i]  = *(const bf16x8*)&As[cur][(wr * 64 + i * 16 + rr) * 32 + kb];
      bfr[i] = *(const bf16x8*)&Bs[cur][(wc * 64 + i * 16 + rr) * 32 + kb];
    }
#pragma unroll
    for (int i = 0; i < 4; ++i)
#pragma unroll
      for (int j = 0; j < 4; ++j)
        acc[i][j] = MF(af[i], bfr[j], acc[i][j]);
    cur ^= 1;
  }

  // C/D layout: col=lane&15, row=(lane>>4)*4+reg  [m89-verified]
  const int cb = n0 + wc * 64 + (lane & 15);
  const int rb = m0 + wr * 64 + ((lane >> 4) << 2);
#pragma unroll
  for (int j = 0; j < 4; ++j) {
    const int c = cb + j * 16;
    float bv = 0.f;
    if constexpr (EPI != EPI_F32 && EPI != EPI_B16) bv = bias[c];
#pragma unroll
    for (int i = 0; i < 4; ++i) {
      const int r0 = rb + i * 16;
#pragma unroll
      for (int r = 0; r < 4; ++r) {
        const size_t idx = (size_t)(r0 + r) * N + c;
        const float v = acc[i][j][r];
        if constexpr (EPI == EPI_F32) {
          outF[idx] = v;
        } else if constexpr (EPI == EPI_GI) {
          outF[idx] = v + bv;
        } else if constexpr (EPI == EPI_TANH) {
          outB[idx] = f2bf(fast_tanh(v + bv));
        } else if constexpr (EPI == EPI_B16) {
          outB[idx] = f2bf(v);
        } else if constexpr (EPI == EPI_Z0) {
          const float tz = v + bv;
          outF[idx] = tz;                        // Z0f (f32, reused all step)
          outB[idx] = f2bf(fast_tanh(tz));       // fused stage-1 h1
        } else if constexpr (EPI == EPI_F1 || EPI == EPI_F23) {
          if (c < 1024) {                        // k-part (bv = b2[c])
            const size_t ix = (size_t)(r0 + r) * 1024 + c;
            const float kv = v + bv;
            if constexpr (EPI == EPI_F1) KACC[ix] = (RKDT / 6.f) * kv;
            else                         KACC[ix] += (RKDT / 3.f) * kv;
          } else {                               // G-part (bv = g0[c-1024])
            const size_t ix = (size_t)(r0 + r) * 1024 + (c - 1024);
            const float Gv = v + bv;
            outB[ix] = f2bf(fast_tanh(Z0[ix] + kgc * Gv));
            if constexpr (EPI == EPI_F1) GACC[ix] = (RKDT / 6.f) * Gv;
            else                         GACC[ix] += (RKDT / 3.f) * Gv;
          }
        } else if constexpr (EPI == EPI_F4) {
          if (c < 1024) {                        // zn update
            const size_t ix = (size_t)(r0 + r) * 1024 + c;
            const float kv = v + bv;
            Z[ix] = Z[ix] + KACC[ix] + (RKDT / 6.f) * kv;
          } else {                               // Z0 advance + next h1
            const size_t ix = (size_t)(r0 + r) * 1024 + (c - 1024);
            const float Gv = v + bv;
            const float z0n = Z0[ix] + GACC[ix] + (RKDT / 6.f) * Gv;
            Z0[ix] = z0n;
            outB[ix] = f2bf(fast_tanh(z0n));
          }
        } else {  // EPI_K4L (N==1024, final step): zn + split-z
          const float kv = v + bv;
          const float zn = Z[idx] + KACC[idx] + (RKDT / 6.f) * kv;
          Z[idx] = zn;
          const size_t si = (size_t)(r0 + r) * 2048 + c;
          const bf16_t hi = f2bf(zn);
          S2[si] = hi;
          S2[si + 1024] = f2bf(zn - (float)hi);
        }
      }
    }
  }
}

// ============================================================================
// Persistent GRU v3 (proven r10/r16): lightweight agent-scope barrier @256blk.
// ============================================================================
__global__ __launch_bounds__(512)
void gru_persistent(const float* __restrict__ gi,   // [TS][512][3072] (bih incl)
                    const bf16_t* __restrict__ Whh, // [3072][1024] bf16
                    const float* __restrict__ bhh,  // [3072]
                    float* __restrict__ Hf,         // [512][1024] f32 persist
                    bf16_t* __restrict__ hb,        // [2][512][2048] split h
                    unsigned int* __restrict__ ctr, // barrier counter (reset=0)
                    float* __restrict__ outp,       // d_out (f32)
                    int TS, int t0)
{
  __shared__ __align__(16) bf16_t Bs[48 * 1032];
  const int tid  = threadIdx.x;
  const int lane = tid & 63;
  const int w    = tid >> 6;
  const int rg   = blockIdx.x >> 6;
  const int jg   = blockIdx.x & 63;
  const int r0   = rg << 7;
  const int j0   = jg << 4;

  for (int it = tid; it < 48 * 128; it += 512) {
    const int rr = it >> 7;
    const int co = (it & 127) << 3;
    const int g = rr >> 4, c = rr & 15;
    *(bf16x8*)&Bs[rr * 1032 + co] =
        *(const bf16x8*)&Whh[(size_t)(g * 1024 + j0 + c) * 1024 + co];
  }

  const int myj = j0 + (lane & 15);
  const float bh_r = bhh[myj], bh_z = bhh[1024 + myj], bh_n = bhh[2048 + myj];
  const int rbase = r0 + w * 16 + ((lane >> 4) << 2);

  float h[4];
#pragma unroll
  for (int q = 0; q < 4; ++q) h[q] = Hf[(size_t)(rbase + q) * 1024 + myj];

  float gpre[12];
  auto load_gi = [&](int lt) {
    const float* gir = gi + (size_t)lt * 512 * 3072;
#pragma unroll
    for (int q = 0; q < 4; ++q) {
      const size_t rr = (size_t)(rbase + q);
      gpre[q * 3 + 0] = gir[rr * 3072 + myj];
      gpre[q * 3 + 1] = gir[rr * 3072 + 1024 + myj];
      gpre[q * 3 + 2] = gir[rr * 3072 + 2048 + myj];
    }
  };
  load_gi(0);

  __syncthreads();

  const int arow = r0 + w * 16 + (lane & 15);
  const int akoff = (lane >> 4) << 3;

  for (int s = 0; s < TS; ++s) {
    const int t = t0 + s;
    const bf16_t* ap = hb + (size_t)(t & 1) * 512 * 2048 +
                       (size_t)arow * 2048 + akoff;
    f32x4 a0 = {}, a1 = {}, a2 = {};
    const bf16_t* bp0 = &Bs[(0  + (lane & 15)) * 1032 + akoff];
    const bf16_t* bp1 = &Bs[(16 + (lane & 15)) * 1032 + akoff];
    const bf16_t* bp2 = &Bs[(32 + (lane & 15)) * 1032 + akoff];
#pragma unroll 8
    for (int kc = 0; kc < 64; ++kc) {
      const bf16x8 af = *(const bf16x8*)(ap + kc * 32);
      const int kl = (kc * 32) & 1023;
      a0 = MF(af, *(const bf16x8*)(bp0 + kl), a0);
      a1 = MF(af, *(const bf16x8*)(bp1 + kl), a1);
      a2 = MF(af, *(const bf16x8*)(bp2 + kl), a2);
    }
    bf16_t* hbw = hb + (size_t)((t + 1) & 1) * 512 * 2048;
#pragma unroll
    for (int q = 0; q < 4; ++q) {
      const size_t rr = (size_t)(rbase + q);
      const float rg_ = fast_sigmoid(gpre[q * 3 + 0] + a0[q] + bh_r);
      const float zg  = fast_sigmoid(gpre[q * 3 + 1] + a1[q] + bh_z);
      const float n   = fast_tanh(gpre[q * 3 + 2] + rg_ * (a2[q] + bh_n));
      h[q] = (1.f - zg) * n + zg * h[q];
      union { __bf16 b; unsigned short u; } uh, ul;
      uh.b = f2bf(h[q]);
      ul.b = f2bf(h[q] - (float)uh.b);
      const unsigned ph = (unsigned)__shfl_xor((int)uh.u, 1) & 0xFFFFu;
      const unsigned pl = (unsigned)__shfl_xor((int)ul.u, 1) & 0xFFFFu;
      if (!(lane & 1)) {
        const unsigned hiw = (unsigned)uh.u | (ph << 16);
        const unsigned low = (unsigned)ul.u | (pl << 16);
        __hip_atomic_store((unsigned*)(hbw + rr * 2048 + myj), hiw,
                           __ATOMIC_RELAXED, __HIP_MEMORY_SCOPE_AGENT);
        __hip_atomic_store((unsigned*)(hbw + rr * 2048 + 1024 + myj), low,
                           __ATOMIC_RELAXED, __HIP_MEMORY_SCOPE_AGENT);
      }
    }
    if (s + 1 < TS) load_gi(s + 1);

    __syncthreads();
    if (tid == 0) {
      __hip_atomic_fetch_add(ctr, 1u, __ATOMIC_RELAXED, __HIP_MEMORY_SCOPE_AGENT);
      const unsigned tgt = 256u * (unsigned)(s + 1);
      while (__hip_atomic_load(ctr, __ATOMIC_ACQUIRE, __HIP_MEMORY_SCOPE_AGENT) < tgt)
        __builtin_amdgcn_s_sleep(1);
    }
    __syncthreads();
  }

#pragma unroll
  for (int q = 0; q < 4; ++q) {
    const int r = rbase + q;
    Hf[(size_t)r * 1024 + myj] = h[q];
    if (myj < 512) outp[(size_t)r * 512 + myj] = h[q];
    else           outp[262144 + (size_t)r * 512 + (myj - 512)] = h[q];
  }
}

__global__ void gru_reset(unsigned int* ctr) {
  if (threadIdx.x == 0)
    __hip_atomic_store(ctr, 0u, __ATOMIC_RELAXED, __HIP_MEMORY_SCOPE_AGENT);
}

// per-row LayerNorm(+bias) + LeakyReLU(0.1), row width 1024.
template<bool SPLIT>
__global__ __launch_bounds__(256)
void ln_leaky(const float* __restrict__ pre, const float* __restrict__ b,
              const float* __restrict__ g, const float* __restrict__ bet,
              bf16_t* __restrict__ outB, float* __restrict__ zf)
{
  const int row = blockIdx.x;
  const int tid = threadIdx.x;
  const float* p = pre + (size_t)row * 1024;
  float v[4];
  float s = 0.f, s2 = 0.f;
#pragma unroll
  for (int i = 0; i < 4; ++i) {
    const int c = tid + i * 256;
    v[i] = p[c] + b[c];
    s += v[i]; s2 += v[i] * v[i];
  }
#pragma unroll
  for (int o = 32; o; o >>= 1) { s += __shfl_down(s, o); s2 += __shfl_down(s2, o); }
  __shared__ float rs[4], rs2[4];
  if ((tid & 63) == 0) { rs[tid >> 6] = s; rs2[tid >> 6] = s2; }
  __syncthreads();
  s = rs[0] + rs[1] + rs[2] + rs[3];
  s2 = rs2[0] + rs2[1] + rs2[2] + rs2[3];
  const float mu = s * (1.f / 1024.f);
  const float var = s2 * (1.f / 1024.f) - mu * mu;
  const float rstd = rsqrtf(var + 1e-5f);
#pragma unroll
  for (int i = 0; i < 4; ++i) {
    const int c = tid + i * 256;
    float h = (v[i] - mu) * rstd * g[c] + bet[c];
    h = h >= 0.f ? h : 0.1f * h;
    if constexpr (SPLIT) {
      const bf16_t hi = f2bf(h);
      outB[(size_t)row * 2048 + c] = hi;
      outB[(size_t)row * 2048 + 1024 + c] = f2bf(h - (float)hi);
      zf[(size_t)row * 1024 + c] = h;
    } else {
      outB[(size_t)row * 1024 + c] = f2bf(h);
    }
  }
}

__global__ __launch_bounds__(256)
void transpose_bf16(const float* __restrict__ in, bf16_t* __restrict__ out, int R, int C)
{
  __shared__ float t[32][33];
  const int c0 = blockIdx.x * 32, r0 = blockIdx.y * 32;
  const int tx = threadIdx.x & 31, ty = threadIdx.x >> 5;
#pragma unroll
  for (int i = 0; i < 32; i += 8)
    t[ty + i][tx] = in[(size_t)(r0 + ty + i) * C + c0 + tx];
  __syncthreads();
#pragma unroll
  for (int i = 0; i < 32; i += 8)
    out[(size_t)(c0 + ty + i) * R + r0 + tx] = f2bf(t[tx][ty + i]);
}

__global__ __launch_bounds__(256)
void f2b_kernel(const float* __restrict__ in, bf16_t* __restrict__ out, int n)
{
  const int i = blockIdx.x * 256 + threadIdx.x;
  if (i < n) out[i] = f2bf(in[i]);
}

__global__ __launch_bounds__(256)
void dup2_kernel(const bf16_t* __restrict__ in, bf16_t* __restrict__ out, int N, int K)
{
  const int idx = blockIdx.x * 256 + threadIdx.x;
  if (idx >= N * 2 * K) return;
  const int n = idx / (2 * K);
  const int kk = idx - n * 2 * K;
  const int k = kk < K ? kk : kk - K;
  out[idx] = in[(size_t)n * K + k];
}

// biasKG[0:1024) = b2 ; biasKG[1024+n] = g0[n] = sum_s b2[s] * W0[s][n]
__global__ __launch_bounds__(256)
void biaskg_kernel(const float* __restrict__ b2, const float* __restrict__ W0,
                   float* __restrict__ biasKG)
{
  const int n = blockIdx.x * 256 + threadIdx.x;  // 1024 threads
  if (n >= 1024) return;
  biasKG[n] = b2[n];
  float s = 0.f;
  for (int ss = 0; ss < 1024; ++ss) s += b2[ss] * W0[(size_t)ss * 1024 + n];
  biasKG[1024 + n] = s;
}

__global__ void sentinel_kernel(float* out, float code) {
  if (threadIdx.x == 0 && blockIdx.x == 0) out[0] = code;
}

extern "C" void kernel_launch(void* const* d_in, const int* in_sizes, int n_in,
                              void* d_out, int out_size, void* d_ws, size_t ws_size,
                              hipStream_t stream)
{
  const float* xs    = (const float*)d_in[0];
  const float* obs_W = (const float*)d_in[1];
  const float* obs_b = (const float*)d_in[2];
  const float* obs_g = (const float*)d_in[3];
  const float* obs_be= (const float*)d_in[4];
  const float* lat_W = (const float*)d_in[5];
  const float* lat_b = (const float*)d_in[6];
  const float* lat_g = (const float*)d_in[7];
  const float* lat_be= (const float*)d_in[8];
  const float* W0    = (const float*)d_in[9];
  const float* b0    = (const float*)d_in[10];
  const float* W1    = (const float*)d_in[11];
  const float* b1    = (const float*)d_in[12];
  const float* W2    = (const float*)d_in[13];
  const float* b2    = (const float*)d_in[14];
  const float* Wih   = (const float*)d_in[15];
  const float* Whh   = (const float*)d_in[16];
  const float* bih   = (const float*)d_in[17];
  const float* bhh   = (const float*)d_in[18];

  char* ws = (char*)d_ws;
  size_t off = 0;
  auto alloc = [&](size_t bytes) { char* p = ws + off; off += bytes; return p; };

  // ---- static region ----
  bf16_t* OBSWT = (bf16_t*)alloc((size_t)HID * OBS * 2);
  bf16_t* LATWT = (bf16_t*)alloc((size_t)STATEDIM * HID * 2);
  bf16_t* W0T   = (bf16_t*)alloc((size_t)HID * STATEDIM * 2);  // A of W20T GEMM
  bf16_t* W0T2  = (bf16_t*)alloc((size_t)HID * 2048 * 2);      // K-dup for Z0
  bf16_t* W1T   = (bf16_t*)alloc((size_t)HID * HID * 2);
  bf16_t* WKG   = (bf16_t*)alloc((size_t)2048 * 1024 * 2);     // [W2T ; W20T]
  bf16_t* W2B   = (bf16_t*)alloc((size_t)HID * STATEDIM * 2);  // temp (plain W2)
  bf16_t* WIH2  = (bf16_t*)alloc((size_t)3072 * 2048 * 2);
  bf16_t* WHHB  = (bf16_t*)alloc((size_t)3072 * 1024 * 2);
  float*  Hf    = (float*)alloc((size_t)512 * 1024 * 4);
  bf16_t* HB2   = (bf16_t*)alloc((size_t)2 * 512 * 2048 * 2);
  bf16_t* WIHB  = (bf16_t*)alloc((size_t)3072 * 1024 * 2);     // temp
  bf16_t* XSB   = (bf16_t*)alloc((size_t)ROWS * OBS * 2);
  float*  biasKG= (float*)alloc((size_t)2048 * 4);
  unsigned int* CTR = (unsigned int*)alloc(128);
  const size_t staticEnd = off;

  // ---- chunking (20480 B/row):
  //   [0,4096)      A1f: enc pre-LN f32 / KACC f32 (RK4)
  //   [4096,8192)   Zf (z f32)
  //   [8192,12288)  Z0f (z@W0+b0 f32)
  //   [12288,14336) H1b   [14336,16384) H2b
  //   [16384,20480) S2b: split-z (LN out, step0-Z0 in, final K4L out, gi in)
  //                 / GACC f32 during RK4 steps (dead split-z window)
  //   GIf (12288 B/row) overlaps A1f+Zf+Z0f (all dead when gi runs).
  int nc = -1;
  const int ncs[8] = {1, 2, 4, 8, 16, 32, 64, 128};
  for (int i = 0; i < 8; ++i) {
    const size_t R = (size_t)ROWS / ncs[i];
    if (staticEnd + R * 20480 <= ws_size) { nc = ncs[i]; break; }
  }
  if (nc < 0) {
    sentinel_kernel<<<1, 1, 0, stream>>>((float*)d_out,
                                         -(1000000.0f + (float)(ws_size >> 20)));
    return;
  }
  const int R = ROWS / nc;
  char* arena = ws + staticEnd;
  float*  A1f  = (float*)(arena);                       // pre-LN scratch
  float*  KACC = (float*)(arena);                       // KACC (overlaps A1f)
  float*  Zf   = (float*)(arena + (size_t)R * 4096);
  float*  Z0f  = (float*)(arena + (size_t)R * 8192);
  bf16_t* H1b  = (bf16_t*)(arena + (size_t)R * 12288);
  bf16_t* H2b  = (bf16_t*)(arena + (size_t)R * 14336);
  bf16_t* S2b  = (bf16_t*)(arena + (size_t)R * 16384);  // split z
  float*  GACC = (float*)(arena + (size_t)R * 16384);   // GACC (overlaps S2b)
  float*  GIf  = (float*)(arena);                       // gi f32 overlaps A1f..Z0f

  auto gemm = [&](int epi, const bf16_t* A, const bf16_t* Wt, const float* bias,
                  int M, int N, int K, float* oF, bf16_t* oB,
                  float kgc = 0.f, int last = 0) {
    dim3 g((M / 128) * (N / 128)), b(256);
    switch (epi) {
      case EPI_F32:  gemm_bt<EPI_F32><<<g, b, 0, stream>>>(A, Wt, bias, M, N, K, oF, oB, Zf, Z0f, S2b, KACC, GACC, kgc, last); break;
      case EPI_GI:   gemm_bt<EPI_GI><<<g, b, 0, stream>>>(A, Wt, bias, M, N, K, oF, oB, Zf, Z0f, S2b, KACC, GACC, kgc, last); break;
      case EPI_TANH: gemm_bt<EPI_TANH><<<g, b, 0, stream>>>(A, Wt, bias, M, N, K, oF, oB, Zf, Z0f, S2b, KACC, GACC, kgc, last); break;
      case EPI_B16:  gemm_bt<EPI_B16><<<g, b, 0, stream>>>(A, Wt, bias, M, N, K, oF, oB, Zf, Z0f, S2b, KACC, GACC, kgc, last); break;
      case EPI_Z0:   gemm_bt<EPI_Z0><<<g, b, 0, stream>>>(A, Wt, bias, M, N, K, oF, oB, Zf, Z0f, S2b, KACC, GACC, kgc, last); break;
      case EPI_F1:   gemm_bt<EPI_F1><<<g, b, 0, stream>>>(A, Wt, bias, M, N, K, oF, oB, Zf, Z0f, S2b, KACC, GACC, kgc, last); break;
      case EPI_F23:  gemm_bt<EPI_F23><<<g, b, 0, stream>>>(A, Wt, bias, M, N, K, oF, oB, Zf, Z0f, S2b, KACC, GACC, kgc, last); break;
      case EPI_F4:   gemm_bt<EPI_F4><<<g, b, 0, stream>>>(A, Wt, bias, M, N, K, oF, oB, Zf, Z0f, S2b, KACC, GACC, kgc, last); break;
      case EPI_K4L:  gemm_bt<EPI_K4L><<<g, b, 0, stream>>>(A, Wt, bias, M, N, K, oF, oB, Zf, Z0f, S2b, KACC, GACC, kgc, last); break;
    }
  };

  // ---- weight prep ----
  transpose_bf16<<<dim3(HID / 32, OBS / 32), 256, 0, stream>>>(obs_W, OBSWT, OBS, HID);
  transpose_bf16<<<dim3(STATEDIM / 32, HID / 32), 256, 0, stream>>>(lat_W, LATWT, HID, STATEDIM);
  transpose_bf16<<<dim3(HID / 32, STATEDIM / 32), 256, 0, stream>>>(W0, W0T, STATEDIM, HID);
  dup2_kernel<<<(HID * 2048) / 256, 256, 0, stream>>>(W0T, W0T2, HID, 1024);
  transpose_bf16<<<dim3(HID / 32, HID / 32), 256, 0, stream>>>(W1, W1T, HID, HID);
  transpose_bf16<<<dim3(STATEDIM / 32, HID / 32), 256, 0, stream>>>(W2, WKG, HID, STATEDIM); // rows 0-1023 = W2T
  f2b_kernel<<<(HID * STATEDIM) / 256, 256, 0, stream>>>(W2, W2B, HID * STATEDIM);
  // W20T[n][k] = sum_s W0T[n][s]*W2B[k][s] = (W2*W0)[k][n] -> WKG rows 1024..2047
  gemm(EPI_B16, W0T, W2B, nullptr, 1024, 1024, 1024, nullptr, WKG + (size_t)1024 * 1024);
  biaskg_kernel<<<4, 256, 0, stream>>>(b2, W0, biasKG);
  f2b_kernel<<<(3072 * 1024) / 256, 256, 0, stream>>>(Wih, WIHB, 3072 * 1024);
  dup2_kernel<<<(3072 * 2048) / 256, 256, 0, stream>>>(WIHB, WIH2, 3072, 1024);
  f2b_kernel<<<(3072 * 1024) / 256, 256, 0, stream>>>(Whh, WHHB, 3072 * 1024);
  f2b_kernel<<<(ROWS * OBS) / 256, 256, 0, stream>>>(xs, XSB, ROWS * OBS);

  hipMemsetAsync(Hf, 0, (size_t)512 * 1024 * 4, stream);
  hipMemsetAsync(HB2, 0, (size_t)2 * 512 * 2048 * 2, stream);
  const int TS = R / BATCHN;

  for (int c = 0; c < nc; ++c) {
    // encoder MLPs
    gemm(EPI_F32, XSB + (size_t)c * R * OBS, OBSWT, nullptr, R, HID, OBS, A1f, nullptr);
    ln_leaky<false><<<R, 256, 0, stream>>>(A1f, obs_b, obs_g, obs_be, H1b, nullptr);
    gemm(EPI_F32, H1b, LATWT, nullptr, R, STATEDIM, HID, A1f, nullptr);
    ln_leaky<true><<<R, 256, 0, stream>>>(A1f, lat_b, lat_g, lat_be, S2b, Zf);

    // step-0 Z0 = z@W0+b0 (exact split K=2048) + fused h1
    gemm(EPI_Z0, S2b, W0T2, b0, R, HID, 2048, Z0f, H1b);

    // RK4: 8 GEMMs/step (TANH + fused [k|G]) — Z0 advanced inside F4
    for (int step = 0; step < 4; ++step) {
      gemm(EPI_TANH, H1b, W1T, b1, R, HID, HID, nullptr, H2b);
      gemm(EPI_F1, H2b, WKG, biasKG, R, 2048, HID, nullptr, H1b, 0.5f * RKDT);
      gemm(EPI_TANH, H1b, W1T, b1, R, HID, HID, nullptr, H2b);
      gemm(EPI_F23, H2b, WKG, biasKG, R, 2048, HID, nullptr, H1b, 0.5f * RKDT);
      gemm(EPI_TANH, H1b, W1T, b1, R, HID, HID, nullptr, H2b);
      gemm(EPI_F23, H2b, WKG, biasKG, R, 2048, HID, nullptr, H1b, RKDT);
      gemm(EPI_TANH, H1b, W1T, b1, R, HID, HID, nullptr, H2b);
      if (step < 3)
        gemm(EPI_F4, H2b, WKG, biasKG, R, 2048, HID, nullptr, H1b);
      else
        gemm(EPI_K4L, H2b, WKG, b2, R, STATEDIM, HID, nullptr, nullptr);
    }

    // gi = z_final @ Wih^T + bih (split-z, f32 out) — overwrites dead A1f..Z0f
    gemm(EPI_GI, S2b, WIH2, bih, R, 3072, 2048, GIf, nullptr);

    // persistent GRU over this chunk's timesteps
    gru_reset<<<1, 64, 0, stream>>>(CTR);
    {
      const float* giArg = GIf;
      const bf16_t* whhArg = WHHB;
      const float* bhhArg = bhh;
      float* hfArg = Hf;
      bf16_t* hbArg = HB2;
      unsigned int* ctrArg = CTR;
      float* outArg = (float*)d_out;
      int tsArg = TS;
      int t0Arg = c * TS;
      void* args[] = { (void*)&giArg, (void*)&whhArg, (void*)&bhhArg,
                       (void*)&hfArg, (void*)&hbArg, (void*)&ctrArg,
                       (void*)&outArg, (void*)&tsArg, (void*)&t0Arg };
      hipLaunchCooperativeKernel((const void*)gru_persistent,
                                 dim3(256), dim3(512), args, 0, stream);
    }
  }
}

// Round 18
// 18766.077 us; speedup vs baseline: 1.1328x; 1.1328x over previous
//
#include <hip/hip_runtime.h>
#include <hip/hip_bf16.h>
#include <hip/hip_cooperative_groups.h>

namespace cg = cooperative_groups;

typedef __bf16 bf16_t;
typedef __bf16 bf16x8 __attribute__((ext_vector_type(8)));
typedef float f32x4 __attribute__((ext_vector_type(4)));

#define TLEN 128
#define BATCHN 512
#define OBS 256
#define HID 1024
#define STATEDIM 1024
#define ROWS (TLEN * BATCHN)   // 65536
#define RKDT 0.25f

// EPI_Z0 : Z0f=v+b (f32) AND h1=tanh(v+b)        (step-0, split-z K=2048)
// EPI_Z0U: Z0f += v; h1=tanh(Z0f)                (steps 1-3, A=dz bf16 K=1024)
// EPI_KW : outB = bf16(v+b)                      (k1,k2,k3 writes)
// EPI_KG : h1 = tanh(Z0f + kgc*v)                (G = k@W0, no bias)
// EPI_K4 : k4=v+b; dz=(dt/6)(k1+2k2+2k3+k4); zn=z+dz; z=zn;
//          last ? write split-S2(zn) : write bf16(dz)
enum { EPI_F32 = 0, EPI_GI, EPI_TANH, EPI_Z0, EPI_Z0U, EPI_KW, EPI_KG, EPI_K4 };

__device__ __forceinline__ void gload_lds16(const bf16_t* g, bf16_t* l) {
  __builtin_amdgcn_global_load_lds(
      (const __attribute__((address_space(1))) void*)g,
      (__attribute__((address_space(3))) void*)l, 16, 0, 0);
}

__device__ __forceinline__ bf16_t f2bf(float x) { return (bf16_t)x; }

// fast tanh/sigmoid on v_exp_f32 (~1e-6 abs err; bf16-invisible)
__device__ __forceinline__ float fast_tanh(float x) {
  const float e = __expf(2.f * x);
  return 1.f - 2.f / (e + 1.f);
}
__device__ __forceinline__ float fast_sigmoid(float x) {
  return 1.f / (1.f + __expf(-x));
}

#define MF(a_, b_, c_) __builtin_amdgcn_mfma_f32_16x16x32_bf16(a_, b_, c_, 0, 0, 0)

// ============================================================================
// m97-structure GEMM + bijective XCD chunk-swizzle (proven r7/r10/r16).
// C = epi(A[M][K] @ Wt[N][K]^T + bias). A,Wt bf16 row-major, fp32 acc.
// 128x128 tile, BK=32, 4 waves (2x2), 16x16x32 MFMA, global_load_lds dbuf.
// Z (z fp32) and Z0 (z@W0 fp32) are RMW in some epilogues -> not __restrict__.
// ============================================================================
template<int EPI>
__global__ __launch_bounds__(256)
void gemm_bt(const bf16_t* __restrict__ A, const bf16_t* __restrict__ Wt,
             const float* __restrict__ bias, int M, int N, int K,
             float* outF, bf16_t* __restrict__ outB,
             float* Z, float* Z0,
             bf16_t* S2,
             const bf16_t* __restrict__ kb1, const bf16_t* __restrict__ kb2,
             const bf16_t* __restrict__ kb3,
             float kgc, int last)
{
  __shared__ __align__(16) bf16_t As[2][128 * 32];
  __shared__ __align__(16) bf16_t Bs[2][128 * 32];
  const int tid = threadIdx.x;
  const int lane = tid & 63;
  const int wave = tid >> 6;
  const int nbn = N >> 7;

  // bijective XCD swizzle (m204): contiguous chunk of blocks per XCD
  int bid = blockIdx.x;
  {
    const int nwg = gridDim.x;
    const int q = nwg >> 3, r = nwg & 7;
    const int xcd = bid & 7, lid = bid >> 3;
    bid = (xcd < r ? xcd * (q + 1) : r * (q + 1) + (xcd - r) * q) + lid;
  }
  const int bm = bid / nbn;
  const int bn = bid % nbn;
  const int m0 = bm << 7, n0 = bn << 7;
  const int wr = wave >> 1, wc = wave & 1;
  const int srow = tid >> 2;          // staging row in tile (0..63)
  const int scol = (tid & 3) << 3;    // staging col (bf16 elems)

  f32x4 acc[4][4] = {};
  const int nk = K >> 5;
  int cur = 0;

  {
    const bf16_t* ga = A  + (size_t)(m0 + srow) * K + scol;
    const bf16_t* gb = Wt + (size_t)(n0 + srow) * K + scol;
    bf16_t* la = &As[0][tid * 8];
    bf16_t* lb = &Bs[0][tid * 8];
    gload_lds16(ga, la);
    gload_lds16(ga + (size_t)64 * K, la + 2048);
    gload_lds16(gb, lb);
    gload_lds16(gb + (size_t)64 * K, lb + 2048);
  }

  for (int ks = 0; ks < nk; ++ks) {
    __syncthreads();  // drains vmcnt(0): staged tile ready
    if (ks + 1 < nk) {
      const bf16_t* ga = A  + (size_t)(m0 + srow) * K + (ks + 1) * 32 + scol;
      const bf16_t* gb = Wt + (size_t)(n0 + srow) * K + (ks + 1) * 32 + scol;
      bf16_t* la = &As[cur ^ 1][tid * 8];
      bf16_t* lb = &Bs[cur ^ 1][tid * 8];
      gload_lds16(ga, la);
      gload_lds16(ga + (size_t)64 * K, la + 2048);
      gload_lds16(gb, lb);
      gload_lds16(gb + (size_t)64 * K, lb + 2048);
    }
    const int kb = (lane >> 4) << 3;
    const int rr = lane & 15;
    bf16x8 af[4], bfr[4];
#pragma unroll
    for (int i = 0; i < 4; ++i) {
      af[i]  = *(const bf16x8*)&As[cur][(wr * 64 + i * 16 + rr) * 32 + kb];
      bfr[i] = *(const bf16x8*)&Bs[cur][(wc * 64 + i * 16 + rr) * 32 + kb];
    }
#pragma unroll
    for (int i = 0; i < 4; ++i)
#pragma unroll
      for (int j = 0; j < 4; ++j)
        acc[i][j] = MF(af[i], bfr[j], acc[i][j]);
    cur ^= 1;
  }

  // C/D layout: col=lane&15, row=(lane>>4)*4+reg  [m89-verified]
  const int cb = n0 + wc * 64 + (lane & 15);
  const int rb = m0 + wr * 64 + ((lane >> 4) << 2);
#pragma unroll
  for (int j = 0; j < 4; ++j) {
    const int c = cb + j * 16;
    float bv = 0.f;
    if constexpr (EPI != EPI_F32 && EPI != EPI_KG && EPI != EPI_Z0U) bv = bias[c];
#pragma unroll
    for (int i = 0; i < 4; ++i) {
      const int r0 = rb + i * 16;
#pragma unroll
      for (int r = 0; r < 4; ++r) {
        const size_t idx = (size_t)(r0 + r) * N + c;
        const float v = acc[i][j][r];
        if constexpr (EPI == EPI_F32) {
          outF[idx] = v;
        } else if constexpr (EPI == EPI_GI) {
          outF[idx] = v + bv;
        } else if constexpr (EPI == EPI_TANH) {
          outB[idx] = f2bf(fast_tanh(v + bv));
        } else if constexpr (EPI == EPI_Z0) {
          const float tz = v + bv;
          outF[idx] = tz;                        // Z0f (f32, reused all step)
          outB[idx] = f2bf(fast_tanh(tz));       // fused stage-1 h1
        } else if constexpr (EPI == EPI_Z0U) {
          const float tz = Z0[idx] + v;          // Z0 += dz@W0  (RMW, same thread)
          Z0[idx] = tz;
          outB[idx] = f2bf(fast_tanh(tz));       // stage-1 h1 of this step
        } else if constexpr (EPI == EPI_KW) {
          outB[idx] = f2bf(v + bv);              // k1/k2/k3 (bf16)
        } else if constexpr (EPI == EPI_KG) {
          outB[idx] = f2bf(fast_tanh(Z0[idx] + kgc * v));
        } else {  // EPI_K4 (N==1024): zn from deferred k-sum
          const float k4 = v + bv;
          const float k1 = (float)kb1[idx];
          const float k2 = (float)kb2[idx];
          const float k3 = (float)kb3[idx];
          const float dz = (RKDT / 6.f) * (k1 + 2.f * k2 + 2.f * k3 + k4);
          const float zn = Z[idx] + dz;
          Z[idx] = zn;
          if (last) {                            // split-z for the gi GEMM
            const size_t si = (size_t)(r0 + r) * 2048 + c;
            const bf16_t hi = f2bf(zn);
            S2[si] = hi;
            S2[si + 1024] = f2bf(zn - (float)hi);
          } else {                               // dz bf16 for Z0-incremental
            S2[idx] = f2bf(dz);
          }
        }
      }
    }
  }
}

// ============================================================================
// Persistent GRU v3 (proven r10/r16/r17-counters): lightweight agent-scope
// barrier at 256 blocks — 430 us/dispatch measured (vs 777 us cg variant).
// ============================================================================
__global__ __launch_bounds__(512)
void gru_persistent(const float* __restrict__ gi,   // [TS][512][3072] (bih incl)
                    const bf16_t* __restrict__ Whh, // [3072][1024] bf16
                    const float* __restrict__ bhh,  // [3072]
                    float* __restrict__ Hf,         // [512][1024] f32 persist
                    bf16_t* __restrict__ hb,        // [2][512][2048] split h
                    unsigned int* __restrict__ ctr, // barrier counter (reset=0)
                    float* __restrict__ outp,       // d_out (f32)
                    int TS, int t0)
{
  __shared__ __align__(16) bf16_t Bs[48 * 1032];
  const int tid  = threadIdx.x;
  const int lane = tid & 63;
  const int w    = tid >> 6;
  const int rg   = blockIdx.x >> 6;
  const int jg   = blockIdx.x & 63;
  const int r0   = rg << 7;
  const int j0   = jg << 4;

  for (int it = tid; it < 48 * 128; it += 512) {
    const int rr = it >> 7;
    const int co = (it & 127) << 3;
    const int g = rr >> 4, c = rr & 15;
    *(bf16x8*)&Bs[rr * 1032 + co] =
        *(const bf16x8*)&Whh[(size_t)(g * 1024 + j0 + c) * 1024 + co];
  }

  const int myj = j0 + (lane & 15);
  const float bh_r = bhh[myj], bh_z = bhh[1024 + myj], bh_n = bhh[2048 + myj];
  const int rbase = r0 + w * 16 + ((lane >> 4) << 2);

  float h[4];
#pragma unroll
  for (int q = 0; q < 4; ++q) h[q] = Hf[(size_t)(rbase + q) * 1024 + myj];

  float gpre[12];
  auto load_gi = [&](int lt) {
    const float* gir = gi + (size_t)lt * 512 * 3072;
#pragma unroll
    for (int q = 0; q < 4; ++q) {
      const size_t rr = (size_t)(rbase + q);
      gpre[q * 3 + 0] = gir[rr * 3072 + myj];
      gpre[q * 3 + 1] = gir[rr * 3072 + 1024 + myj];
      gpre[q * 3 + 2] = gir[rr * 3072 + 2048 + myj];
    }
  };
  load_gi(0);

  __syncthreads();

  const int arow = r0 + w * 16 + (lane & 15);
  const int akoff = (lane >> 4) << 3;

  for (int s = 0; s < TS; ++s) {
    const int t = t0 + s;
    const bf16_t* ap = hb + (size_t)(t & 1) * 512 * 2048 +
                       (size_t)arow * 2048 + akoff;
    f32x4 a0 = {}, a1 = {}, a2 = {};
    const bf16_t* bp0 = &Bs[(0  + (lane & 15)) * 1032 + akoff];
    const bf16_t* bp1 = &Bs[(16 + (lane & 15)) * 1032 + akoff];
    const bf16_t* bp2 = &Bs[(32 + (lane & 15)) * 1032 + akoff];
#pragma unroll 8
    for (int kc = 0; kc < 64; ++kc) {
      const bf16x8 af = *(const bf16x8*)(ap + kc * 32);
      const int kl = (kc * 32) & 1023;
      a0 = MF(af, *(const bf16x8*)(bp0 + kl), a0);
      a1 = MF(af, *(const bf16x8*)(bp1 + kl), a1);
      a2 = MF(af, *(const bf16x8*)(bp2 + kl), a2);
    }
    bf16_t* hbw = hb + (size_t)((t + 1) & 1) * 512 * 2048;
#pragma unroll
    for (int q = 0; q < 4; ++q) {
      const size_t rr = (size_t)(rbase + q);
      const float rg_ = fast_sigmoid(gpre[q * 3 + 0] + a0[q] + bh_r);
      const float zg  = fast_sigmoid(gpre[q * 3 + 1] + a1[q] + bh_z);
      const float n   = fast_tanh(gpre[q * 3 + 2] + rg_ * (a2[q] + bh_n));
      h[q] = (1.f - zg) * n + zg * h[q];
      union { __bf16 b; unsigned short u; } uh, ul;
      uh.b = f2bf(h[q]);
      ul.b = f2bf(h[q] - (float)uh.b);
      const unsigned ph = (unsigned)__shfl_xor((int)uh.u, 1) & 0xFFFFu;
      const unsigned pl = (unsigned)__shfl_xor((int)ul.u, 1) & 0xFFFFu;
      if (!(lane & 1)) {
        const unsigned hiw = (unsigned)uh.u | (ph << 16);
        const unsigned low = (unsigned)ul.u | (pl << 16);
        __hip_atomic_store((unsigned*)(hbw + rr * 2048 + myj), hiw,
                           __ATOMIC_RELAXED, __HIP_MEMORY_SCOPE_AGENT);
        __hip_atomic_store((unsigned*)(hbw + rr * 2048 + 1024 + myj), low,
                           __ATOMIC_RELAXED, __HIP_MEMORY_SCOPE_AGENT);
      }
    }
    if (s + 1 < TS) load_gi(s + 1);

    __syncthreads();
    if (tid == 0) {
      __hip_atomic_fetch_add(ctr, 1u, __ATOMIC_RELAXED, __HIP_MEMORY_SCOPE_AGENT);
      const unsigned tgt = 256u * (unsigned)(s + 1);
      while (__hip_atomic_load(ctr, __ATOMIC_ACQUIRE, __HIP_MEMORY_SCOPE_AGENT) < tgt)
        __builtin_amdgcn_s_sleep(1);
    }
    __syncthreads();
  }

#pragma unroll
  for (int q = 0; q < 4; ++q) {
    const int r = rbase + q;
    Hf[(size_t)r * 1024 + myj] = h[q];
    if (myj < 512) outp[(size_t)r * 512 + myj] = h[q];
    else           outp[262144 + (size_t)r * 512 + (myj - 512)] = h[q];
  }
}

__global__ void gru_reset(unsigned int* ctr) {
  if (threadIdx.x == 0)
    __hip_atomic_store(ctr, 0u, __ATOMIC_RELAXED, __HIP_MEMORY_SCOPE_AGENT);
}

// per-row LayerNorm(+bias) + LeakyReLU(0.1), row width 1024.
template<bool SPLIT>
__global__ __launch_bounds__(256)
void ln_leaky(const float* __restrict__ pre, const float* __restrict__ b,
              const float* __restrict__ g, const float* __restrict__ bet,
              bf16_t* __restrict__ outB, float* __restrict__ zf)
{
  const int row = blockIdx.x;
  const int tid = threadIdx.x;
  const float* p = pre + (size_t)row * 1024;
  float v[4];
  float s = 0.f, s2 = 0.f;
#pragma unroll
  for (int i = 0; i < 4; ++i) {
    const int c = tid + i * 256;
    v[i] = p[c] + b[c];
    s += v[i]; s2 += v[i] * v[i];
  }
#pragma unroll
  for (int o = 32; o; o >>= 1) { s += __shfl_down(s, o); s2 += __shfl_down(s2, o); }
  __shared__ float rs[4], rs2[4];
  if ((tid & 63) == 0) { rs[tid >> 6] = s; rs2[tid >> 6] = s2; }
  __syncthreads();
  s = rs[0] + rs[1] + rs[2] + rs[3];
  s2 = rs2[0] + rs2[1] + rs2[2] + rs2[3];
  const float mu = s * (1.f / 1024.f);
  const float var = s2 * (1.f / 1024.f) - mu * mu;
  const float rstd = rsqrtf(var + 1e-5f);
#pragma unroll
  for (int i = 0; i < 4; ++i) {
    const int c = tid + i * 256;
    float h = (v[i] - mu) * rstd * g[c] + bet[c];
    h = h >= 0.f ? h : 0.1f * h;
    if constexpr (SPLIT) {
      const bf16_t hi = f2bf(h);
      outB[(size_t)row * 2048 + c] = hi;
      outB[(size_t)row * 2048 + 1024 + c] = f2bf(h - (float)hi);
      zf[(size_t)row * 1024 + c] = h;
    } else {
      outB[(size_t)row * 1024 + c] = f2bf(h);
    }
  }
}

__global__ __launch_bounds__(256)
void transpose_bf16(const float* __restrict__ in, bf16_t* __restrict__ out, int R, int C)
{
  __shared__ float t[32][33];
  const int c0 = blockIdx.x * 32, r0 = blockIdx.y * 32;
  const int tx = threadIdx.x & 31, ty = threadIdx.x >> 5;
#pragma unroll
  for (int i = 0; i < 32; i += 8)
    t[ty + i][tx] = in[(size_t)(r0 + ty + i) * C + c0 + tx];
  __syncthreads();
#pragma unroll
  for (int i = 0; i < 32; i += 8)
    out[(size_t)(c0 + ty + i) * R + r0 + tx] = f2bf(t[tx][ty + i]);
}

__global__ __launch_bounds__(256)
void f2b_kernel(const float* __restrict__ in, bf16_t* __restrict__ out, int n)
{
  const int i = blockIdx.x * 256 + threadIdx.x;
  if (i < n) out[i] = f2bf(in[i]);
}

__global__ __launch_bounds__(256)
void dup2_kernel(const bf16_t* __restrict__ in, bf16_t* __restrict__ out, int N, int K)
{
  const int idx = blockIdx.x * 256 + threadIdx.x;
  if (idx >= N * 2 * K) return;
  const int n = idx / (2 * K);
  const int kk = idx - n * 2 * K;
  const int k = kk < K ? kk : kk - K;
  out[idx] = in[(size_t)n * K + k];
}

__global__ void sentinel_kernel(float* out, float code) {
  if (threadIdx.x == 0 && blockIdx.x == 0) out[0] = code;
}

extern "C" void kernel_launch(void* const* d_in, const int* in_sizes, int n_in,
                              void* d_out, int out_size, void* d_ws, size_t ws_size,
                              hipStream_t stream)
{
  const float* xs    = (const float*)d_in[0];
  const float* obs_W = (const float*)d_in[1];
  const float* obs_b = (const float*)d_in[2];
  const float* obs_g = (const float*)d_in[3];
  const float* obs_be= (const float*)d_in[4];
  const float* lat_W = (const float*)d_in[5];
  const float* lat_b = (const float*)d_in[6];
  const float* lat_g = (const float*)d_in[7];
  const float* lat_be= (const float*)d_in[8];
  const float* W0    = (const float*)d_in[9];
  const float* b0    = (const float*)d_in[10];
  const float* W1    = (const float*)d_in[11];
  const float* b1    = (const float*)d_in[12];
  const float* W2    = (const float*)d_in[13];
  const float* b2    = (const float*)d_in[14];
  const float* Wih   = (const float*)d_in[15];
  const float* Whh   = (const float*)d_in[16];
  const float* bih   = (const float*)d_in[17];
  const float* bhh   = (const float*)d_in[18];

  char* ws = (char*)d_ws;
  size_t off = 0;
  auto alloc = [&](size_t bytes) { char* p = ws + off; off += bytes; return p; };

  // ---- static region ----
  bf16_t* OBSWT = (bf16_t*)alloc((size_t)HID * OBS * 2);
  bf16_t* LATWT = (bf16_t*)alloc((size_t)STATEDIM * HID * 2);
  bf16_t* W0T   = (bf16_t*)alloc((size_t)HID * STATEDIM * 2);  // for KG / Z0U GEMMs
  bf16_t* W0T2  = (bf16_t*)alloc((size_t)HID * 2048 * 2);      // K-dup for split-z Z0
  bf16_t* W1T   = (bf16_t*)alloc((size_t)HID * HID * 2);
  bf16_t* W2T   = (bf16_t*)alloc((size_t)STATEDIM * HID * 2);
  bf16_t* WIH2  = (bf16_t*)alloc((size_t)3072 * 2048 * 2);
  bf16_t* WHHB  = (bf16_t*)alloc((size_t)3072 * 1024 * 2);
  float*  Hf    = (float*)alloc((size_t)512 * 1024 * 4);
  bf16_t* HB2   = (bf16_t*)alloc((size_t)2 * 512 * 2048 * 2);
  bf16_t* WIHB  = (bf16_t*)alloc((size_t)3072 * 1024 * 2);     // temp
  bf16_t* XSB   = (bf16_t*)alloc((size_t)ROWS * OBS * 2);      // bf16 input
  unsigned int* CTR = (unsigned int*)alloc(128);               // barrier counter
  const size_t staticEnd = off;

  // ---- chunking (22528 B/row, r10/r11/r16 layout):
  //   [0,4096)    A1f: enc pre-LN scratch; during steps: KB1|KB2 (bf16 k1,k2)
  //   [4096,8192) Zf (z fp32)
  //   [8192,12288) Z0f (z@W0+b0 fp32)
  //   [12288,14336) H1b  [14336,16384) H2b  [16384,18432) KB3 (k3)
  //   [18432,22528) S2b: split-z (LN & final K4) / dz bf16 (non-final K4)
  //   GIf (12288 B/row) overlaps A1f+Zf+Z0f (all dead when gi runs).
  int nc = -1;
  const int ncs[8] = {1, 2, 4, 8, 16, 32, 64, 128};
  for (int i = 0; i < 8; ++i) {
    const size_t R = (size_t)ROWS / ncs[i];
    if (staticEnd + R * 22528 <= ws_size) { nc = ncs[i]; break; }
  }
  if (nc < 0) {
    sentinel_kernel<<<1, 1, 0, stream>>>((float*)d_out,
                                         -(1000000.0f + (float)(ws_size >> 20)));
    return;
  }
  const int R = ROWS / nc;
  char* arena = ws + staticEnd;
  float*  A1f  = (float*)(arena);                       // pre-LN scratch
  bf16_t* KB1  = (bf16_t*)(arena);                      // k1 (overlaps A1f lo)
  bf16_t* KB2  = (bf16_t*)(arena + (size_t)R * 2048);   // k2 (overlaps A1f hi)
  float*  Zf   = (float*)(arena + (size_t)R * 4096);
  float*  Z0f  = (float*)(arena + (size_t)R * 8192);
  bf16_t* H1b  = (bf16_t*)(arena + (size_t)R * 12288);
  bf16_t* H2b  = (bf16_t*)(arena + (size_t)R * 14336);
  bf16_t* KB3  = (bf16_t*)(arena + (size_t)R * 16384);
  bf16_t* S2b  = (bf16_t*)(arena + (size_t)R * 18432);  // split z / dz
  bf16_t* DZb  = S2b;                                   // dz bf16 ([R][1024])
  float*  GIf  = (float*)(arena);                       // gi f32 overlaps A1f..Z0f

  auto gemm = [&](int epi, const bf16_t* A, const bf16_t* Wt, const float* bias,
                  int M, int N, int K, float* oF, bf16_t* oB,
                  float kgc = 0.f, int last = 0) {
    dim3 g((M / 128) * (N / 128)), b(256);
    switch (epi) {
      case EPI_F32:  gemm_bt<EPI_F32><<<g, b, 0, stream>>>(A, Wt, bias, M, N, K, oF, oB, Zf, Z0f, S2b, KB1, KB2, KB3, kgc, last); break;
      case EPI_GI:   gemm_bt<EPI_GI><<<g, b, 0, stream>>>(A, Wt, bias, M, N, K, oF, oB, Zf, Z0f, S2b, KB1, KB2, KB3, kgc, last); break;
      case EPI_TANH: gemm_bt<EPI_TANH><<<g, b, 0, stream>>>(A, Wt, bias, M, N, K, oF, oB, Zf, Z0f, S2b, KB1, KB2, KB3, kgc, last); break;
      case EPI_Z0:   gemm_bt<EPI_Z0><<<g, b, 0, stream>>>(A, Wt, bias, M, N, K, oF, oB, Zf, Z0f, S2b, KB1, KB2, KB3, kgc, last); break;
      case EPI_Z0U:  gemm_bt<EPI_Z0U><<<g, b, 0, stream>>>(A, Wt, bias, M, N, K, oF, oB, Zf, Z0f, S2b, KB1, KB2, KB3, kgc, last); break;
      case EPI_KW:   gemm_bt<EPI_KW><<<g, b, 0, stream>>>(A, Wt, bias, M, N, K, oF, oB, Zf, Z0f, S2b, KB1, KB2, KB3, kgc, last); break;
      case EPI_KG:   gemm_bt<EPI_KG><<<g, b, 0, stream>>>(A, Wt, bias, M, N, K, oF, oB, Zf, Z0f, S2b, KB1, KB2, KB3, kgc, last); break;
      case EPI_K4:   gemm_bt<EPI_K4><<<g, b, 0, stream>>>(A, Wt, bias, M, N, K, oF, oB, Zf, Z0f, S2b, KB1, KB2, KB3, kgc, last); break;
    }
  };

  // ---- weight prep ----
  transpose_bf16<<<dim3(HID / 32, OBS / 32), 256, 0, stream>>>(obs_W, OBSWT, OBS, HID);
  transpose_bf16<<<dim3(STATEDIM / 32, HID / 32), 256, 0, stream>>>(lat_W, LATWT, HID, STATEDIM);
  transpose_bf16<<<dim3(HID / 32, STATEDIM / 32), 256, 0, stream>>>(W0, W0T, STATEDIM, HID);
  dup2_kernel<<<(HID * 2048) / 256, 256, 0, stream>>>(W0T, W0T2, HID, 1024);
  transpose_bf16<<<dim3(HID / 32, HID / 32), 256, 0, stream>>>(W1, W1T, HID, HID);
  transpose_bf16<<<dim3(STATEDIM / 32, HID / 32), 256, 0, stream>>>(W2, W2T, HID, STATEDIM);
  f2b_kernel<<<(3072 * 1024) / 256, 256, 0, stream>>>(Wih, WIHB, 3072 * 1024);
  dup2_kernel<<<(3072 * 2048) / 256, 256, 0, stream>>>(WIHB, WIH2, 3072, 1024);
  f2b_kernel<<<(3072 * 1024) / 256, 256, 0, stream>>>(Whh, WHHB, 3072 * 1024);
  f2b_kernel<<<(ROWS * OBS) / 256, 256, 0, stream>>>(xs, XSB, ROWS * OBS);

  hipMemsetAsync(Hf, 0, (size_t)512 * 1024 * 4, stream);
  hipMemsetAsync(HB2, 0, (size_t)2 * 512 * 2048 * 2, stream);
  const int TS = R / BATCHN;  // timesteps per chunk

  for (int c = 0; c < nc; ++c) {
    // encoder MLPs for this chunk of rows
    gemm(EPI_F32, XSB + (size_t)c * R * OBS, OBSWT, nullptr, R, HID, OBS, A1f, nullptr);
    ln_leaky<false><<<R, 256, 0, stream>>>(A1f, obs_b, obs_g, obs_be, H1b, nullptr);
    gemm(EPI_F32, H1b, LATWT, nullptr, R, STATEDIM, HID, A1f, nullptr);
    ln_leaky<true><<<R, 256, 0, stream>>>(A1f, lat_b, lat_g, lat_be, S2b, Zf);

    // RK4, per step (12 GEMMs):
    //   step0: Z0 split (exact). steps1-3: Z0 += dz@W0 (incremental).
    //   stages: TANH -> KW(k_i) -> KG(h1_{i+1}) x3, final TANH -> K4.
    for (int step = 0; step < 4; ++step) {
      if (step == 0) gemm(EPI_Z0, S2b, W0T2, b0, R, HID, 2048, Z0f, H1b);
      else           gemm(EPI_Z0U, DZb, W0T, nullptr, R, HID, 1024, nullptr, H1b);
      gemm(EPI_TANH, H1b, W1T, b1, R, HID, HID, nullptr, H2b);
      gemm(EPI_KW, H2b, W2T, b2, R, STATEDIM, HID, nullptr, KB1);
      gemm(EPI_KG, KB1, W0T, nullptr, R, HID, STATEDIM, nullptr, H1b, 0.5f * RKDT);
      gemm(EPI_TANH, H1b, W1T, b1, R, HID, HID, nullptr, H2b);
      gemm(EPI_KW, H2b, W2T, b2, R, STATEDIM, HID, nullptr, KB2);
      gemm(EPI_KG, KB2, W0T, nullptr, R, HID, STATEDIM, nullptr, H1b, 0.5f * RKDT);
      gemm(EPI_TANH, H1b, W1T, b1, R, HID, HID, nullptr, H2b);
      gemm(EPI_KW, H2b, W2T, b2, R, STATEDIM, HID, nullptr, KB3);
      gemm(EPI_KG, KB3, W0T, nullptr, R, HID, STATEDIM, nullptr, H1b, RKDT);
      gemm(EPI_TANH, H1b, W1T, b1, R, HID, HID, nullptr, H2b);
      gemm(EPI_K4, H2b, W2T, b2, R, STATEDIM, HID, nullptr, nullptr, 0.f,
           (step == 3) ? 1 : 0);
    }

    // gi = z_final @ Wih^T + bih (split-z, fp32 out) — overwrites dead A1f..Z0f
    gemm(EPI_GI, S2b, WIH2, bih, R, 3072, 2048, GIf, nullptr);

    // persistent GRU over this chunk's timesteps
    gru_reset<<<1, 64, 0, stream>>>(CTR);
    {
      const float* giArg = GIf;
      const bf16_t* whhArg = WHHB;
      const float* bhhArg = bhh;
      float* hfArg = Hf;
      bf16_t* hbArg = HB2;
      unsigned int* ctrArg = CTR;
      float* outArg = (float*)d_out;
      int tsArg = TS;
      int t0Arg = c * TS;
      void* args[] = { (void*)&giArg, (void*)&whhArg, (void*)&bhhArg,
                       (void*)&hfArg, (void*)&hbArg, (void*)&ctrArg,
                       (void*)&outArg, (void*)&tsArg, (void*)&t0Arg };
      hipLaunchCooperativeKernel((const void*)gru_persistent,
                                 dim3(256), dim3(512), args, 0, stream);
    }
  }
}